// Round 10
// baseline (92.927 us; speedup 1.0000x reference)
//
#include <hip/hip_runtime.h>
#include <stdint.h>
#include <math.h>

#define CC 22
#define START_I 20
#define STOP_I 21
#define BB 64
#define LL 512
#define DD 512
#define NEGV -100000.0f
#define NCH 32
#define CS 16

// ws layout
#define EMIT_FLOATS ((BB * LL + CS) * CC)                // + CS rows slack
#define BP_OFF (((EMIT_FLOATS * 4) + 255) & ~255)
#define BP_BYTES (BB * LL * CC)
#define META_OFF ((BP_OFF + BP_BYTES + 255) & ~255)
#define PV_OFF (META_OFF + 1024)                         // 64*32*22 floats = 180224 B
#define PHI_OFF (PV_OFF + BB * NCH * CC * 4)             // 64*32*22*22 floats = 3.96 MB

// ---------------- emissions GEMM: emit[row][c] = x[row]·W[c] + b[c] ----------------
// 4 rows x 2 classes per thread: 4 global float4 + 2 LDS b128 per 32 FMA.
// Per-output k-ascending x/y/z/w summation order: bit-identical to prior rounds.
__global__ __launch_bounds__(256) void k_emit(const float* __restrict__ x,
                                              const float* __restrict__ W,
                                              const float* __restrict__ bias,
                                              float* __restrict__ emit) {
  __shared__ float Wl[CC * 516];  // row-major, stride 516 (16B aligned, bank-spread)
  int tid = threadIdx.x;
#pragma unroll
  for (int it = 0; it < (CC * DD) / 256; ++it) {
    int g = it * 256 + tid;
    int c = g >> 9;
    int d = g & (DD - 1);
    Wl[c * 516 + d] = W[g];
  }
  __syncthreads();
  int gtid = blockIdx.x * 256 + tid;  // 352*256 = 90112 = 11 * 8192 exactly
  int c = gtid % 11;
  int rq = gtid / 11;                 // row-quad [0, 8192)
  float b0 = bias[c];
  float b1 = bias[c + 11];
  const float4* x0 = (const float4*)(x + (size_t)rq * 4 * DD);  // 4 consecutive rows
  const float* w0 = Wl + c * 516;
  const float* w1 = Wl + (c + 11) * 516;
  float a00 = 0.f, a01 = 0.f, a10 = 0.f, a11 = 0.f;
  float a20 = 0.f, a21 = 0.f, a30 = 0.f, a31 = 0.f;
#pragma unroll 4
  for (int i = 0; i < DD / 4; ++i) {
    float4 r0 = x0[i];
    float4 r1 = x0[i + 128];
    float4 r2 = x0[i + 256];
    float4 r3 = x0[i + 384];
    float4 u = *(const float4*)(w0 + 4 * i);
    float4 v = *(const float4*)(w1 + 4 * i);
    a00 += r0.x * u.x + r0.y * u.y + r0.z * u.z + r0.w * u.w;
    a01 += r0.x * v.x + r0.y * v.y + r0.z * v.z + r0.w * v.w;
    a10 += r1.x * u.x + r1.y * u.y + r1.z * u.z + r1.w * u.w;
    a11 += r1.x * v.x + r1.y * v.y + r1.z * v.z + r1.w * v.w;
    a20 += r2.x * u.x + r2.y * u.y + r2.z * u.z + r2.w * u.w;
    a21 += r2.x * v.x + r2.y * v.y + r2.z * v.z + r2.w * v.w;
    a30 += r3.x * u.x + r3.y * u.y + r3.z * u.z + r3.w * u.w;
    a31 += r3.x * v.x + r3.y * v.y + r3.z * v.z + r3.w * v.w;
  }
  size_t r0i = (size_t)rq * 4;
  emit[(r0i + 0) * CC + c] = a00 + b0;
  emit[(r0i + 0) * CC + c + 11] = a01 + b1;
  emit[(r0i + 1) * CC + c] = a10 + b0;
  emit[(r0i + 1) * CC + c + 11] = a11 + b1;
  emit[(r0i + 2) * CC + c] = a20 + b0;
  emit[(r0i + 2) * CC + c + 11] = a21 + b1;
  emit[(r0i + 3) * CC + c] = a30 + b0;
  emit[(r0i + 3) * CC + c + 11] = a31 + b1;
}

__device__ __forceinline__ float rlf(float v, int l) {
  return __int_as_float(__builtin_amdgcn_readlane(__float_as_int(v), l));
}

// ---------------- segment transfer matrices (parallel-in-time Viterbi) ----------
__global__ __launch_bounds__(256) void k_seg(const float* __restrict__ emit,
                                             const float* __restrict__ mask,
                                             const float* __restrict__ trans,
                                             float* __restrict__ phi) {
  __shared__ float Ph[2][CC][23];
  __shared__ float els[CS * CC];
  const int seg = blockIdx.x, b = blockIdx.y;
  const int tid = threadIdx.x;
  const int lane = tid & 63;
  int n = 0;  // each wave computes redundantly (no sync needed)
#pragma unroll
  for (int k = 0; k < 8; ++k)
    n += __popcll(__ballot(mask[(size_t)b * LL + k * 64 + lane] > 0.0f));
  const int t0 = seg * CS;
  for (int i = tid; i < CS * CC; i += 256)  // FIX: full 352-entry fill
    els[i] = emit[((size_t)b * LL + t0) * CC + i];
  const bool own = tid < 242;
  const int to2 = own ? tid / CC : 0;   // 0..10
  const int frm0 = own ? tid % CC : 0;  // 0..21
  float T0[CC], T1[CC];
  if (own) {
#pragma unroll
    for (int f = 0; f < CC; ++f) {
      T0[f] = trans[to2 * CC + f];
      T1[f] = trans[(to2 + 11) * CC + f];
    }
    Ph[0][to2][frm0] = (to2 == frm0) ? 0.0f : -INFINITY;
    Ph[0][to2 + 11][frm0] = (to2 + 11 == frm0) ? 0.0f : -INFINITY;
  }
  __syncthreads();
  int steps = n - t0;
  steps = steps < 0 ? 0 : (steps > CS ? CS : steps);
  int c = 0;
  for (int q = 0; q < steps; ++q) {  // block-uniform trip count
    if (own) {
      float a0 = -INFINITY, a1 = -INFINITY;
#pragma unroll
      for (int f = 0; f < CC; ++f) {
        float v = Ph[c][f][frm0];
        a0 = fmaxf(a0, v + T0[f]);
        a1 = fmaxf(a1, v + T1[f]);
      }
      Ph[c ^ 1][to2][frm0] = a0 + els[q * CC + to2];
      Ph[c ^ 1][to2 + 11][frm0] = a1 + els[q * CC + to2 + 11];
    }
    __syncthreads();
    c ^= 1;
  }
  if (own) {
    float* pb = phi + ((size_t)b * NCH + seg) * CC * CC;
    pb[to2 * CC + frm0] = Ph[c][to2][frm0];
    pb[(to2 + 11) * CC + frm0] = Ph[c][to2 + 11][frm0];
  }
}

// ---------------- compose: 32 matrix-vector max-plus steps per batch ----------
__global__ __launch_bounds__(64) void k_cmp(const float* __restrict__ phi,
                                            const float* __restrict__ mask,
                                            const float* __restrict__ trans,
                                            float* __restrict__ out_score,
                                            float* __restrict__ pv,
                                            int* __restrict__ meta) {
  const int b = blockIdx.x;
  const int lane = threadIdx.x;
  const int lc = lane < CC ? lane : CC - 1;
  const float Tstop = trans[STOP_I * CC + lc];
  int n = 0;
#pragma unroll
  for (int k = 0; k < 8; ++k)
    n += __popcll(__ballot(mask[(size_t)b * LL + k * 64 + lane] > 0.0f));

  float st = (lane == START_I) ? 0.0f : NEGV;
  const float* pb = phi + (size_t)b * NCH * CC * CC;
  float row[CC], nrow[CC];
#pragma unroll
  for (int f = 0; f < CC; ++f) row[f] = pb[lc * CC + f];
  for (int s = 0; s < NCH; ++s) {
    if (lane < CC) pv[((size_t)b * NCH + s) * CC + lane] = st;
    if (s + 1 < NCH) {
#pragma unroll
      for (int f = 0; f < CC; ++f) nrow[f] = pb[((s + 1) * CC + lc) * CC + f];
    }
    float a = -INFINITY;
#pragma unroll
    for (int f = 0; f < CC; ++f) a = fmaxf(a, row[f] + rlf(st, f));
    st = a;  // identity segments preserve st exactly
#pragma unroll
    for (int f = 0; f < CC; ++f) row[f] = nrow[f];
  }

  float fin = st + Tstop;
  if (lane < CC) out_score[b * CC + lane] = fin;
  float bv = -3.0e38f;
  int bt = 0;
#pragma unroll
  for (int k = 0; k < CC; ++k) {
    float v = rlf(fin, k);
    bool g = v > bv;
    bv = g ? v : bv;
    bt = g ? k : bt;
  }
  if (lane == 0) { meta[b] = n; meta[BB + b] = bt; }
}

// ---------------- parallel replay: backpointers from checkpoints ----------------
__global__ __launch_bounds__(64) void k_rep(const float* __restrict__ emit,
                                            const float* __restrict__ trans,
                                            const float* __restrict__ pv,
                                            const int* __restrict__ meta,
                                            unsigned char* __restrict__ bp) {
  const int c = blockIdx.x, b = blockIdx.y;
  const int lane = threadIdx.x;
  const int n = meta[b];
  const int t0 = c * CS;
  if (t0 >= n) return;
  const int lc = lane < CC ? lane : CC - 1;
  float Trow[CC];
#pragma unroll
  for (int j = 0; j < CC; ++j) Trow[j] = trans[lc * CC + j];
  float st = pv[((size_t)b * NCH + c) * CC + lc];
  const float* eb = emit + (size_t)b * LL * CC;
  float ev[CS];
#pragma unroll
  for (int q = 0; q < CS; ++q) {
    ev[q] = eb[(t0 + q) * CC + lc];
    asm volatile("" : "+v"(ev[q]));
  }
  unsigned char* bpb = bp + (size_t)b * LL * CC;
  const int m = (n - t0) < CS ? (n - t0) : CS;
#pragma unroll
  for (int q = 0; q < CS; ++q) {
    if (q < m) {
      float cand[CC];
#pragma unroll
      for (int j = 0; j < CC; ++j) cand[j] = rlf(st, j) + Trow[j];
      float m0 = fmaxf(fmaxf(cand[0], cand[1]), cand[2]);
      float m1 = fmaxf(fmaxf(cand[3], cand[4]), cand[5]);
      float m2 = fmaxf(fmaxf(cand[6], cand[7]), cand[8]);
      float m3 = fmaxf(fmaxf(cand[9], cand[10]), cand[11]);
      float m4 = fmaxf(fmaxf(cand[12], cand[13]), cand[14]);
      float m5 = fmaxf(fmaxf(cand[15], cand[16]), cand[17]);
      float m6 = fmaxf(fmaxf(cand[18], cand[19]), cand[20]);
      float n0 = fmaxf(fmaxf(m0, m1), m2);
      float n1 = fmaxf(fmaxf(m3, m4), m5);
      float n2 = fmaxf(m6, cand[21]);
      float mx = fmaxf(fmaxf(n0, n1), n2);
      unsigned u = 0;
#pragma unroll
      for (int j = 0; j < CC; ++j) u |= (cand[j] == mx) ? (1u << j) : 0u;
      int bpi = __builtin_ctz(u);
      if (lane < CC) bpb[(t0 + q) * CC + lane] = (unsigned char)bpi;
      st = mx + ev[q];
    }
  }
}

// ---------------- backtrace: chunk-composed backpointer maps ----------------
__global__ __launch_bounds__(64) void k_back(const unsigned char* __restrict__ bp,
                                             const int* __restrict__ meta,
                                             float* __restrict__ out_path) {
  __shared__ __align__(16) unsigned char bps[LL * CC];  // 11264 B
  __shared__ unsigned char gs[64 * CC];
  const int b = blockIdx.x, lane = threadIdx.x;
  const int n = meta[b];
  const int bt = meta[BB + b];
  const uint32_t* src = (const uint32_t*)(bp + (size_t)b * LL * CC);
  uint32_t* dst = (uint32_t*)bps;
  for (int i = lane; i < (LL * CC) / 4; i += 64) dst[i] = src[i];
  __syncthreads();
  const int k = lane;
  for (int c = 0; c < CC; ++c) {
    int tag = c;
#pragma unroll
    for (int j = 7; j >= 0; --j) {
      int t = 8 * k + j;
      int nv = bps[t * CC + tag];
      tag = (t < n) ? nv : tag;
    }
    gs[k * CC + c] = (unsigned char)tag;
  }
  __syncthreads();
  int tag = bt, entry = bt;
  for (int kk = 63; kk >= 0; --kk) {
    if (lane == kk) entry = tag;
    tag = gs[kk * CC + tag];
  }
  tag = entry;
  float* op = out_path + (size_t)b * LL;
#pragma unroll
  for (int j = 7; j >= 0; --j) {
    int t = 8 * k + j;
    bool act = t < n;
    op[t] = act ? (float)tag : 0.0f;
    int nv = bps[t * CC + tag];
    tag = act ? nv : tag;
  }
}

extern "C" void kernel_launch(void* const* d_in, const int* in_sizes, int n_in,
                              void* d_out, int out_size, void* d_ws, size_t ws_size,
                              hipStream_t stream) {
  const float* x = (const float*)d_in[0];
  const float* mask = (const float*)d_in[1];
  const float* W = (const float*)d_in[2];
  const float* bias = (const float*)d_in[3];
  const float* trans = (const float*)d_in[4];
  float* out_score = (float*)d_out;                 // [B, C] f32
  float* out_path = (float*)d_out + BB * CC;        // [B, L] as f32 values
  char* ws = (char*)d_ws;
  float* emit = (float*)ws;
  unsigned char* bp = (unsigned char*)(ws + BP_OFF);
  int* meta = (int*)(ws + META_OFF);
  float* pvp = (float*)(ws + PV_OFF);
  float* phi = (float*)(ws + PHI_OFF);

  k_emit<<<dim3(352), dim3(256), 0, stream>>>(x, W, bias, emit);
  k_seg<<<dim3(NCH, BB), dim3(256), 0, stream>>>(emit, mask, trans, phi);
  k_cmp<<<dim3(BB), dim3(64), 0, stream>>>(phi, mask, trans, out_score, pvp, meta);
  k_rep<<<dim3(NCH, BB), dim3(64), 0, stream>>>(emit, trans, pvp, meta, bp);
  k_back<<<dim3(BB), dim3(64), 0, stream>>>(bp, meta, out_path);
}